// Round 5
// baseline (2381.836 us; speedup 1.0000x reference)
//
#include <hip/hip_runtime.h>
#include <cstdint>
#include <cstddef>

#define NB 16
#define NC 64
#define HW 4096
#define SLICE ((size_t)(NB*NC*HW))   // 4194304 floats per state
#define NSTEP 16
#define GRIDB 256

// ws layout (float offsets)
#define WS_WT    ((size_t)0)          // wT  [16][3][64 o][64 c] = 196608
#define WS_BV    ((size_t)196608)     // bvec[16][64]            = 1024
#define WS_LATT  ((size_t)197632)     // latT[512][16]           = 8192
#define WS_SV    ((size_t)205824)     // sv  [16][3][64]         = 3072
#define WS_SVMU  ((size_t)208896)     // svmu[16][3][64]         = 3072
#define WS_BAR   ((size_t)211968)     // barrier cnt/gen (2 uints)

typedef _Float16 half8 __attribute__((ext_vector_type(8)));  // 8 f16 (4 VGPRs)
typedef float f32x4 __attribute__((ext_vector_type(4)));     // MFMA acc

struct SharedA2 {
  float img[2][4096];
  float red[2][4][6];
};
struct SharedB2 {
  alignas(16) float rawL[2][6400];       // per grp: [c_rel][3 rows*64 px], pad 200
  alignas(16) _Float16 Bhi[2][6144];     // per grp: [c8][px 192][cj 8]
  alignas(16) _Float16 Blo[2][6144];
  alignas(16) _Float16 Whi[12288];       // [kc][g][o][c_rel 32], slot-swizzled
  alignas(16) _Float16 Wlo[12288];
  float svL[192], svmuL[192], biasL[192], bvecL[64];
};
union SharedU { SharedA2 a; SharedB2 b; };

__global__ void k_latT(const float* __restrict__ lat, float* __restrict__ latT,
                       unsigned* __restrict__ bar) {
  int t = threadIdx.x;
  if (t == 0) { bar[0] = 0u; bar[1] = 0u; }
  for (int idx = t; idx < 16*512; idx += 256) {
    int b = idx >> 9, k = idx & 511;
    latT[k*16 + b] = lat[idx];
  }
}

// wT[b][g][o][c] = (lat @ Wk + bk) at j = o*192 + (g*64+c) ; bvec = lat @ Wb + bb
__global__ __launch_bounds__(256) void k_w(const float* __restrict__ latT,
    const float* __restrict__ Wk, const float* __restrict__ bk,
    const float* __restrict__ Wb, const float* __restrict__ bb,
    float* __restrict__ wT, float* __restrict__ bvec) {
  int t = threadIdx.x;
  if (blockIdx.x < 48) {
    int j = blockIdx.x*256 + t;
    float acc[16];
#pragma unroll
    for (int b = 0; b < 16; b++) acc[b] = 0.f;
#pragma unroll 4
    for (int k = 0; k < 512; k++) {
      float wv = Wk[(size_t)k*12288 + j];
      const float* lt = (const float*)__builtin_assume_aligned(latT + k*16, 64);
#pragma unroll
      for (int b = 0; b < 16; b++) acc[b] = fmaf(lt[b], wv, acc[b]);
    }
    int o = j / 192, cf = j % 192;
    int g = cf >> 6, c = cf & 63;
    float bkj = bk[j];
#pragma unroll
    for (int b = 0; b < 16; b++)
      wT[(((size_t)(b*3 + g))*64 + o)*64 + c] = acc[b] + bkj;
  } else if (t < 64) {
    int j = t;
    float acc[16];
#pragma unroll
    for (int b = 0; b < 16; b++) acc[b] = 0.f;
    for (int k = 0; k < 512; k++) {
      float wv = Wb[k*64 + j];
      const float* lt = (const float*)__builtin_assume_aligned(latT + k*16, 64);
#pragma unroll
      for (int b = 0; b < 16; b++) acc[b] = fmaf(lt[b], wv, acc[b]);
    }
    float bbj = bb[j];
#pragma unroll
    for (int b = 0; b < 16; b++) bvec[b*64 + j] = acc[b] + bbj;
  }
}

// ---- grid barrier (GRIDB blocks, cooperative launch) ----
__device__ __forceinline__ void gridbar(unsigned* bar) {
  __syncthreads();
  if (threadIdx.x == 0) {
    __threadfence();
    unsigned g = __hip_atomic_load(&bar[1], __ATOMIC_RELAXED, __HIP_MEMORY_SCOPE_AGENT);
    unsigned v = __hip_atomic_fetch_add(&bar[0], 1u, __ATOMIC_ACQ_REL, __HIP_MEMORY_SCOPE_AGENT);
    if (v == (unsigned)(GRIDB - 1)) {
      __hip_atomic_store(&bar[0], 0u, __ATOMIC_RELAXED, __HIP_MEMORY_SCOPE_AGENT);
      __hip_atomic_fetch_add(&bar[1], 1u, __ATOMIC_RELEASE, __HIP_MEMORY_SCOPE_AGENT);
    } else {
      while (__hip_atomic_load(&bar[1], __ATOMIC_ACQUIRE, __HIP_MEMORY_SCOPE_AGENT) == g)
        __builtin_amdgcn_s_sleep(1);
    }
    __threadfence();
  }
  __syncthreads();
}

// ---- phase A: per (b,c) moments of st, gx, gy -> sv, sv*mu (one unit per group) ----
__device__ void phaseA2(SharedU& sh, int grp, int t8, int vb,
                        const float* __restrict__ st,
                        float* __restrict__ svb, float* __restrict__ svmub) {
  int c = vb & 63, b = vb >> 6;
  __syncthreads();
  const size_t chan = (size_t)(b*NC + c) * HW;
  const float4* src4 = (const float4*)(st + chan);
  float4* img4 = (float4*)sh.a.img[grp];
#pragma unroll
  for (int i = 0; i < 4; i++) img4[i*256 + t8] = src4[i*256 + t8];
  __syncthreads();
  const float* img = sh.a.img[grp];
  float s0=0,q0=0,s1=0,q1=0,s2=0,q2=0;
#pragma unroll
  for (int i = 0; i < 4; i++) {
    int base = i*1024 + t8*4;
    int h = base >> 6, w0 = base & 63;
#pragma unroll
    for (int jj = 0; jj < 4; jj++) {
      int w = w0 + jj;
      bool wl = (w > 0), wr = (w < 63), hu = (h > 0), hd = (h < 63);
      float a00 = (hu && wl) ? img[(h-1)*64 + (w-1)] : 0.f;
      float a01 =  hu        ? img[(h-1)*64 +  w   ] : 0.f;
      float a02 = (hu && wr) ? img[(h-1)*64 + (w+1)] : 0.f;
      float a10 =  wl        ? img[ h   *64 + (w-1)] : 0.f;
      float a12 =  wr        ? img[ h   *64 + (w+1)] : 0.f;
      float a20 = (hd && wl) ? img[(h+1)*64 + (w-1)] : 0.f;
      float a21 =  hd        ? img[(h+1)*64 +  w   ] : 0.f;
      float a22 = (hd && wr) ? img[(h+1)*64 + (w+1)] : 0.f;
      float v = img[h*64 + w];
      float gx = (a02 - a00 + 2.f*(a12 - a10) + a22 - a20) * 0.125f;
      float gy = (a20 - a00 + 2.f*(a21 - a01) + a22 - a02) * 0.125f;
      s0 += v;  q0 = fmaf(v, v, q0);
      s1 += gx; q1 = fmaf(gx, gx, q1);
      s2 += gy; q2 = fmaf(gy, gy, q2);
    }
  }
#pragma unroll
  for (int off = 32; off >= 1; off >>= 1) {
    s0 += __shfl_xor(s0, off); q0 += __shfl_xor(q0, off);
    s1 += __shfl_xor(s1, off); q1 += __shfl_xor(q1, off);
    s2 += __shfl_xor(s2, off); q2 += __shfl_xor(q2, off);
  }
  int lane = t8 & 63, wv = t8 >> 6;
  if (lane == 0) {
    sh.a.red[grp][wv][0]=s0; sh.a.red[grp][wv][1]=q0; sh.a.red[grp][wv][2]=s1;
    sh.a.red[grp][wv][3]=q1; sh.a.red[grp][wv][4]=s2; sh.a.red[grp][wv][5]=q2;
  }
  __syncthreads();
  if (t8 == 0) {
    float r[6];
#pragma unroll
    for (int u = 0; u < 6; u++)
      r[u] = sh.a.red[grp][0][u]+sh.a.red[grp][1][u]+sh.a.red[grp][2][u]+sh.a.red[grp][3][u];
#pragma unroll
    for (int g = 0; g < 3; g++) {
      float mu  = r[2*g] * (1.f/HW);
      float var = fmaxf(r[2*g+1]*(1.f/HW) - mu*mu, 0.f);
      float sv  = 1.f / sqrtf(var + 1e-5f);
      svb  [b*192 + g*64 + c] = sv;
      svmub[b*192 + g*64 + c] = sv * mu;
    }
  }
}

// ---- per-step prelude: load sv/bvec, stage scaled W (both kc) + bias, once per block ----
__device__ void stepB_prelude(SharedU& sh, int b, int t,
    const float* __restrict__ wT, const float* __restrict__ bvec,
    const float* __restrict__ svb, const float* __restrict__ svmub) {
  __syncthreads();
  if (t < 192) { sh.b.svL[t] = svb[b*192 + t]; sh.b.svmuL[t] = svmub[b*192 + t]; }
  if (t < 64) sh.b.bvecL[t] = bvec[b*64 + t];
  __syncthreads();
  if (t < 192) {
    int gso = t >> 6, o = t & 63;
    float biasacc = 0.f;
#pragma unroll
    for (int kc = 0; kc < 2; kc++) {
      const float* wrow = wT + (((size_t)(b*3 + gso))*64 + o)*64 + kc*32;
#pragma unroll
      for (int s = 0; s < 4; s++) {
        float4 va = *(const float4*)(wrow + s*8);
        float4 vb4 = *(const float4*)(wrow + s*8 + 4);
        float wv[8] = {va.x,va.y,va.z,va.w,vb4.x,vb4.y,vb4.z,vb4.w};
        half8 hv, lv;
#pragma unroll
        for (int jj = 0; jj < 8; jj++) {
          int cg = gso*64 + kc*32 + s*8 + jj;
          float scaled = wv[jj] * sh.b.svL[cg];
          biasacc = fmaf(wv[jj], sh.b.svmuL[cg], biasacc);
          _Float16 h = (_Float16)scaled;
          hv[jj] = h;
          lv[jj] = (_Float16)(scaled - (float)h);
        }
        int sidx = kc*6144 + (gso*64 + o)*32 + ((s ^ (o & 3)) << 3);
        *(half8*)(sh.b.Whi + sidx) = hv;
        *(half8*)(sh.b.Wlo + sidx) = lv;
      }
    }
    sh.b.biasL[t] = biasacc;
  }
  __syncthreads();
}

// ---- one unit: row r of batch b (per group) ----
__device__ void unitB(SharedU& sh, int grp, int t8, int b, int r,
                      const float* __restrict__ st, float* __restrict__ stn,
                      float leak) {
  int lane = t8 & 63;
  int wt = t8 >> 6;
  const float* stb = st + (size_t)b*NC*HW;
  f32x4 accA[4] = {}; f32x4 accB[12] = {}; f32x4 accC[12] = {};

  for (int kc = 0; kc < 2; kc++) {
    __syncthreads();   // protect rawL/B-planes reuse
    // ---- stage raw st window (3 rows x 32 channels), full rows ----
#pragma unroll
    for (int i = 0; i < 6; i++) {
      int u = t8 + i*256;            // [0,1536) float4 units
      int c_rel = u / 48, q = u % 48;
      int rho = q >> 4, quad = q & 15;
      int row = r - 1 + rho;
      float4 v = make_float4(0.f,0.f,0.f,0.f);
      if (row >= 0 && row < 64)
        v = *(const float4*)(stb + (size_t)(kc*32 + c_rel)*HW + row*64 + quad*4);
      *(float4*)(sh.b.rawL[grp] + c_rel*200 + rho*64 + quad*4) = v;
    }
    __syncthreads();
    // ---- transpose rawL -> cj-packed f16 hi/lo planes ----
#pragma unroll
    for (int i = 0; i < 3; i++) {
      int v = t8 + i*256;            // 768 units
      int c8 = v / 192, px = v % 192;
      half8 hv, lv;
#pragma unroll
      for (int ii = 0; ii < 8; ii++) {
        float x = sh.b.rawL[grp][(c8*8 + ii)*200 + px];
        _Float16 h = (_Float16)x;
        hv[ii] = h;
        lv[ii] = (_Float16)(x - (float)h);
      }
      *(half8*)(sh.b.Bhi[grp] + (c8*192 + px)*8) = hv;
      *(half8*)(sh.b.Blo[grp] + (c8*192 + px)*8) = lv;
    }
    __syncthreads();
    // ---- MFMA ----
    half8 ahi[3], alo[3];
#pragma unroll
    for (int gso = 0; gso < 3; gso++) {
      int oa = wt*16 + (lane & 15);
      int sidx = kc*6144 + (gso*64 + oa)*32 + (((lane >> 4) ^ (oa & 3)) << 3);
      ahi[gso] = *(const half8*)(sh.b.Whi + sidx);
      alo[gso] = *(const half8*)(sh.b.Wlo + sidx);
    }
#pragma unroll
    for (int n = 0; n < 12; n++) {
      int bidx = ((lane >> 4)*192 + n*16 + (lane & 15))*8;
      half8 bh = *(const half8*)(sh.b.Bhi[grp] + bidx);
      half8 bl = *(const half8*)(sh.b.Blo[grp] + bidx);
      accB[n] = __builtin_amdgcn_mfma_f32_16x16x32_f16(ahi[1], bh, accB[n], 0,0,0);
      accB[n] = __builtin_amdgcn_mfma_f32_16x16x32_f16(ahi[1], bl, accB[n], 0,0,0);
      accB[n] = __builtin_amdgcn_mfma_f32_16x16x32_f16(alo[1], bh, accB[n], 0,0,0);
      accC[n] = __builtin_amdgcn_mfma_f32_16x16x32_f16(ahi[2], bh, accC[n], 0,0,0);
      accC[n] = __builtin_amdgcn_mfma_f32_16x16x32_f16(ahi[2], bl, accC[n], 0,0,0);
      accC[n] = __builtin_amdgcn_mfma_f32_16x16x32_f16(alo[2], bh, accC[n], 0,0,0);
      if (n >= 4 && n < 8) {
        accA[n-4] = __builtin_amdgcn_mfma_f32_16x16x32_f16(ahi[0], bh, accA[n-4], 0,0,0);
        accA[n-4] = __builtin_amdgcn_mfma_f32_16x16x32_f16(ahi[0], bl, accA[n-4], 0,0,0);
        accA[n-4] = __builtin_amdgcn_mfma_f32_16x16x32_f16(alo[0], bh, accA[n-4], 0,0,0);
      }
    }
  }

  // ---- epilogue: in-register sobel on mixed images + bias + residual ----
#pragma unroll
  for (int j = 0; j < 4; j++) {
    int o = wt*16 + ((lane >> 4) << 2) + j;
    float Sx[4], Sy[4];
#pragma unroll
    for (int nc = 0; nc < 4; nc++) {
      Sx[nc] = accB[nc][j] + 2.f*accB[4+nc][j] + accB[8+nc][j];
      Sy[nc] = accC[8+nc][j] - accC[nc][j];
    }
    float bt = sh.b.bvecL[o] - sh.b.biasL[o] - sh.b.biasL[64+o] - sh.b.biasL[128+o];
#pragma unroll
    for (int nc = 0; nc < 4; nc++) {
      int nm = (nc > 0) ? nc-1 : 0;
      int np = (nc < 3) ? nc+1 : 3;
      float xl1 = __shfl(Sx[nc], (lane - 1) & 63);
      float xl2 = (nc > 0) ? __shfl(Sx[nm], (lane + 15) & 63) : 0.f;
      float xL  = (lane & 15) ? xl1 : xl2;
      float xr1 = __shfl(Sx[nc], (lane + 1) & 63);
      float xr2 = (nc < 3) ? __shfl(Sx[np], (lane - 15) & 63) : 0.f;
      float xR  = ((lane & 15) == 15) ? xr2 : xr1;
      float yl1 = __shfl(Sy[nc], (lane - 1) & 63);
      float yl2 = (nc > 0) ? __shfl(Sy[nm], (lane + 15) & 63) : 0.f;
      float yL  = (lane & 15) ? yl1 : yl2;
      float yr1 = __shfl(Sy[nc], (lane + 1) & 63);
      float yr2 = (nc < 3) ? __shfl(Sy[np], (lane - 15) & 63) : 0.f;
      float yR  = ((lane & 15) == 15) ? yr2 : yr1;
      float gx = (xR - xL) * 0.125f;
      float gy = (yL + 2.f*Sy[nc] + yR) * 0.125f;
      float nw = accA[nc][j] + gx + gy + bt;
      int w = nc*16 + (lane & 15);
      size_t gi = (size_t)(b*NC + o)*HW + (size_t)r*64 + w;
      stn[gi] = st[gi] + leak * nw;
    }
  }
}

// ---- one persistent cooperative kernel: init + 16 steps + final ----
__global__ __launch_bounds__(512, 2) void k_steps(float* __restrict__ embs,
    const float* __restrict__ wT, const float* __restrict__ bvec,
    float* __restrict__ svb, float* __restrict__ svmub,
    const float* __restrict__ leakp, float* __restrict__ out0,
    float* __restrict__ out2, unsigned* __restrict__ bar) {
  __shared__ SharedU sh;
  int bid = blockIdx.x, t = threadIdx.x;
  int grp = t >> 8, t8 = t & 255;

  // init: embs slice 0 = zeros except [b][0][32][32] = 1
#pragma unroll
  for (int i = 0; i < 8; i++) {
    int u = bid*4096 + i*512 + t;
    int idx4 = u*4;
    float4 v = make_float4(0.f, 0.f, 0.f, 0.f);
    if ((idx4 & 262143) == 2080) v.x = 1.0f;
    *(float4*)(embs + idx4) = v;
  }
  gridbar(bar);

  float leak = fminf(fmaxf(leakp[0], 0.001f), 1000.f);
  int b = bid >> 4, r0 = bid & 15;
  for (int step = 0; step < NSTEP; step++) {
    const float* stc = embs + (size_t)step*SLICE;
    float*       stn = embs + (size_t)(step+1)*SLICE;
    phaseA2(sh, grp, t8, (bid<<2) | 0 | grp, stc, svb, svmub);
    phaseA2(sh, grp, t8, (bid<<2) | 2 | grp, stc, svb, svmub);
    gridbar(bar);
    stepB_prelude(sh, b, t, wT, bvec, svb, svmub);
    unitB(sh, grp, t8, b, r0 + (grp<<4),      stc, stn, leak);
    unitB(sh, grp, t8, b, r0 + (grp<<4) + 32, stc, stn, leak);
    gridbar(bar);
  }

  // final: clip(final[:, :3]) -> out0 ; raw -> out2
  const float* stF = embs + (size_t)NSTEP*SLICE;
  int u = bid*512 + t;
  if (u < 49152) {
    int i4 = u*4;
    int bb2 = i4 / 12288, rr = i4 % 12288;
    float4 v = *(const float4*)(stF + (size_t)bb2*(NC*HW) + rr);
    float4 cv;
    cv.x = fminf(fmaxf(v.x,-1.f),1.f);
    cv.y = fminf(fmaxf(v.y,-1.f),1.f);
    cv.z = fminf(fmaxf(v.z,-1.f),1.f);
    cv.w = fminf(fmaxf(v.w,-1.f),1.f);
    *(float4*)(out0 + i4) = cv;
    *(float4*)(out2 + i4) = v;
  }
}

extern "C" void kernel_launch(void* const* d_in, const int* in_sizes, int n_in,
                              void* d_out, int out_size, void* d_ws, size_t ws_size,
                              hipStream_t stream) {
  const float* lat   = (const float*)d_in[0];
  const float* Wk    = (const float*)d_in[1];
  const float* bk    = (const float*)d_in[2];
  const float* Wb    = (const float*)d_in[3];
  const float* bb    = (const float*)d_in[4];
  const float* leakp = (const float*)d_in[5];
  float* out = (float*)d_out;
  float* ws  = (float*)d_ws;
  float* wT    = ws + WS_WT;
  float* bvec  = ws + WS_BV;
  float* latT  = ws + WS_LATT;
  float* svbuf = ws + WS_SV;
  float* svmub = ws + WS_SVMU;
  unsigned* bar = (unsigned*)(ws + WS_BAR);
  float* out0 = out;
  float* embs = out + 196608;
  float* out2 = out + 196608 + 17*SLICE;

  hipLaunchKernelGGL(k_latT, dim3(1),  dim3(256), 0, stream, lat, latT, bar);
  hipLaunchKernelGGL(k_w,    dim3(49), dim3(256), 0, stream, latT, Wk, bk, Wb, bb, wT, bvec);

  void* args[] = { &embs, &wT, &bvec, &svbuf, &svmub, (void*)&leakp,
                   &out0, &out2, &bar };
  hipLaunchCooperativeKernel((void*)k_steps, dim3(GRIDB), dim3(512),
                             args, 0, stream);
}

// Round 6
// 599.861 us; speedup vs baseline: 3.9706x; 3.9706x over previous
//
#include <hip/hip_runtime.h>
#include <cstdint>
#include <cstddef>

#define NB 16
#define NC 64
#define HW 4096
#define SLICE ((size_t)(NB*NC*HW))   // 4194304 floats per state
#define NSTEP 16

// ws layout (float offsets)
#define WS_WT    ((size_t)0)          // wT  [16][3][64 o][64 c] = 196608
#define WS_BV    ((size_t)196608)     // bvec[16][64]            = 1024
#define WS_LATT  ((size_t)197632)     // latT[512][16]           = 8192
#define WS_SV    ((size_t)205824)     // sv  [16][3][64]         = 3072
#define WS_SVMU  ((size_t)208896)     // svmu[16][3][64]         = 3072

typedef _Float16 half8 __attribute__((ext_vector_type(8)));  // 8 f16 (4 VGPRs)
typedef float f32x4 __attribute__((ext_vector_type(4)));     // MFMA acc

__global__ void k_latT(const float* __restrict__ lat, float* __restrict__ latT) {
  int t = threadIdx.x;
  for (int idx = t; idx < 16*512; idx += 256) {
    int b = idx >> 9, k = idx & 511;
    latT[k*16 + b] = lat[idx];
  }
}

// wT[b][g][o][c] = (lat @ Wk + bk) at j = o*192 + (g*64+c) ; bvec = lat @ Wb + bb
__global__ __launch_bounds__(256) void k_w(const float* __restrict__ latT,
    const float* __restrict__ Wk, const float* __restrict__ bk,
    const float* __restrict__ Wb, const float* __restrict__ bb,
    float* __restrict__ wT, float* __restrict__ bvec) {
  int t = threadIdx.x;
  if (blockIdx.x < 48) {
    int j = blockIdx.x*256 + t;
    float acc[16];
#pragma unroll
    for (int b = 0; b < 16; b++) acc[b] = 0.f;
#pragma unroll 4
    for (int k = 0; k < 512; k++) {
      float wv = Wk[(size_t)k*12288 + j];
      const float* lt = (const float*)__builtin_assume_aligned(latT + k*16, 64);
#pragma unroll
      for (int b = 0; b < 16; b++) acc[b] = fmaf(lt[b], wv, acc[b]);
    }
    int o = j / 192, cf = j % 192;
    int g = cf >> 6, c = cf & 63;
    float bkj = bk[j];
#pragma unroll
    for (int b = 0; b < 16; b++)
      wT[(((size_t)(b*3 + g))*64 + o)*64 + c] = acc[b] + bkj;
  } else if (t < 64) {
    int j = t;
    float acc[16];
#pragma unroll
    for (int b = 0; b < 16; b++) acc[b] = 0.f;
    for (int k = 0; k < 512; k++) {
      float wv = Wb[k*64 + j];
      const float* lt = (const float*)__builtin_assume_aligned(latT + k*16, 64);
#pragma unroll
      for (int b = 0; b < 16; b++) acc[b] = fmaf(lt[b], wv, acc[b]);
    }
    float bbj = bb[j];
#pragma unroll
    for (int b = 0; b < 16; b++) bvec[b*64 + j] = acc[b] + bbj;
  }
}

__global__ void k_init(float* __restrict__ e0) {
  int idx4 = (blockIdx.x*256 + threadIdx.x) * 4;
  float4 v = make_float4(0.f, 0.f, 0.f, 0.f);
  if ((idx4 & 262143) == 2080) v.x = 1.0f;  // 32*64+32, channel 0
  *(float4*)(e0 + idx4) = v;
}

// per (b,c): moments of st, gx, gy via separable sobel, column-sliding.
// thread = (column w, row band h0); all LDS reads lane-stride 4B (conflict-free).
__global__ __launch_bounds__(256) void k_stats(const float* __restrict__ st,
    float* __restrict__ svb, float* __restrict__ svmub) {
  int c = blockIdx.x, b = blockIdx.y, t = threadIdx.x;
  __shared__ float img[HW];
  __shared__ float red[4][6];
  const size_t chan = (size_t)(b*NC + c) * HW;
  const float4* src4 = (const float4*)(st + chan);
  float4* img4 = (float4*)img;
#pragma unroll
  for (int i = 0; i < 4; i++) img4[i*256 + t] = src4[i*256 + t];
  __syncthreads();

  int w = t & 63;
  int h0 = (t >> 6) * 16;          // wave-uniform row band
  bool wl = (w > 0), wr = (w < 63);
  float s0=0,q0=0,s1=0,q1=0,s2=0,q2=0;
  float d_prev=0.f, s_prev=0.f, d_cur, s_cur, v_cur;
  if (h0 > 0) {
    const float* row = img + (h0-1)*64;
    float xl = wl ? row[w-1] : 0.f;
    float xc = row[w];
    float xr = wr ? row[w+1] : 0.f;
    d_prev = xr - xl; s_prev = xl + 2.f*xc + xr;
  }
  {
    const float* row = img + h0*64;
    float xl = wl ? row[w-1] : 0.f;
    float xc = row[w];
    float xr = wr ? row[w+1] : 0.f;
    d_cur = xr - xl; s_cur = xl + 2.f*xc + xr; v_cur = xc;
  }
#pragma unroll
  for (int k = 0; k < 16; k++) {
    int hn = h0 + k + 1;
    float d_nxt=0.f, s_nxt=0.f, v_nxt=0.f;
    if (hn < 64) {                  // wave-uniform branch
      const float* row = img + hn*64;
      float xl = wl ? row[w-1] : 0.f;
      float xc = row[w];
      float xr = wr ? row[w+1] : 0.f;
      d_nxt = xr - xl; s_nxt = xl + 2.f*xc + xr; v_nxt = xc;
    }
    float gx = (d_prev + 2.f*d_cur + d_nxt) * 0.125f;
    float gy = (s_nxt - s_prev) * 0.125f;
    float v = v_cur;
    s0 += v;  q0 = fmaf(v, v, q0);
    s1 += gx; q1 = fmaf(gx, gx, q1);
    s2 += gy; q2 = fmaf(gy, gy, q2);
    d_prev = d_cur; s_prev = s_cur;
    d_cur = d_nxt; s_cur = s_nxt; v_cur = v_nxt;
  }
#pragma unroll
  for (int off = 32; off >= 1; off >>= 1) {
    s0 += __shfl_xor(s0, off); q0 += __shfl_xor(q0, off);
    s1 += __shfl_xor(s1, off); q1 += __shfl_xor(q1, off);
    s2 += __shfl_xor(s2, off); q2 += __shfl_xor(q2, off);
  }
  int lane = t & 63, wv = t >> 6;
  if (lane == 0) {
    red[wv][0]=s0; red[wv][1]=q0; red[wv][2]=s1;
    red[wv][3]=q1; red[wv][4]=s2; red[wv][5]=q2;
  }
  __syncthreads();
  if (t == 0) {
    float r[6];
#pragma unroll
    for (int u = 0; u < 6; u++) r[u] = red[0][u]+red[1][u]+red[2][u]+red[3][u];
#pragma unroll
    for (int g = 0; g < 3; g++) {
      float mu  = r[2*g] * (1.f/HW);
      float var = fmaxf(r[2*g+1]*(1.f/HW) - mu*mu, 0.f);
      float sv  = 1.f / sqrtf(var + 1e-5f);
      svb  [b*192 + g*64 + c] = sv;
      svmub[b*192 + g*64 + c] = sv * mu;
    }
  }
}

struct SB {
  alignas(16) _Float16 Bhi[6144];   // [c8][px^c8][cj]
  alignas(16) _Float16 Blo[6144];
  alignas(16) _Float16 Whi[6144];   // [g][o][slot-swizzled c_rel]
  alignas(16) _Float16 Wlo[6144];
  float svL[192], svmuL[192], biasL[192], bvecL[64];
};  // ~51.7 KB -> 2 blocks/CU (LDS), VGPR-capped at 256

// Fused: mix raw st with scaled W (MFMA f16 hi/lo), sobel AFTER mix, residual.
// 1D grid 1024, XCD-swizzled: xcd = bid&7 owns row band [8*xcd, 8*xcd+8).
__global__ __launch_bounds__(256, 2) void k_fused(const float* __restrict__ st,
    float* __restrict__ stn, const float* __restrict__ wT,
    const float* __restrict__ bvec, const float* __restrict__ svb,
    const float* __restrict__ svmub, const float* __restrict__ leakp,
    float* __restrict__ out0, float* __restrict__ out2, int last) {
  __shared__ SB sh;
  int bid = blockIdx.x, t = threadIdx.x;
  int b = bid >> 6;
  int r = (bid & 7) * 8 + ((bid >> 3) & 7);
  int lane = t & 63, wt = t >> 6;
  const float* stb = st + (size_t)b*NC*HW;
  float leak = fminf(fmaxf(leakp[0], 0.001f), 1000.f);

  if (t < 192) { sh.svL[t] = svb[b*192 + t]; sh.svmuL[t] = svmub[b*192 + t]; }
  if (t < 64) sh.bvecL[t] = bvec[b*64 + t];

  float biasacc = 0.f;
  f32x4 accA[4] = {}; f32x4 accB[12] = {}; f32x4 accC[12] = {};
  float xw0[3][8], xw1[3][8];

  // ---- direct transposed window load: unit u=(c8,pxu); 8 channel-strided floats ----
#define LOADW(KC, XW)                                                    \
  _Pragma("unroll")                                                      \
  for (int i = 0; i < 3; i++) {                                          \
    int u = t + i*256;                                                   \
    int c8 = u / 192, pxu = u % 192;                                     \
    int rho = pxu >> 6, ww = pxu & 63;                                   \
    int row = r - 1 + rho;                                               \
    bool ok = (row >= 0) && (row < 64);                                  \
    int rowc = ok ? row : 0;                                             \
    const float* gp = stb + (size_t)((KC)*32 + c8*8)*HW + rowc*64 + ww;  \
    _Pragma("unroll")                                                    \
    for (int ii = 0; ii < 8; ii++) {                                     \
      float val = gp[(size_t)ii*HW];                                     \
      XW[i][ii] = ok ? val : 0.f;                                        \
    }                                                                    \
  }

  // ---- pack regs -> cj-packed f16 hi/lo planes (XOR px swizzle) ----
#define PACKW(XW)                                                        \
  _Pragma("unroll")                                                      \
  for (int i = 0; i < 3; i++) {                                          \
    int u = t + i*256;                                                   \
    int c8 = u / 192, pxu = u % 192;                                     \
    half8 hv, lv;                                                        \
    _Pragma("unroll")                                                    \
    for (int ii = 0; ii < 8; ii++) {                                     \
      float x = XW[i][ii];                                               \
      _Float16 h = (_Float16)x;                                          \
      hv[ii] = h;                                                        \
      lv[ii] = (_Float16)(x - (float)h);                                 \
    }                                                                    \
    int di = (c8*192 + (pxu ^ c8)) * 8;                                  \
    *(half8*)(sh.Bhi + di) = hv;                                         \
    *(half8*)(sh.Blo + di) = lv;                                         \
  }

  // ---- stage scaled W (hi/lo f16) for one kc + accumulate bias dot ----
#define WSTAGE(KC)                                                       \
  if (t < 192) {                                                         \
    int g = t >> 6, o = t & 63;                                          \
    const float* wrow = wT + (((size_t)(b*3 + g))*64 + o)*64 + (KC)*32;  \
    _Pragma("unroll")                                                    \
    for (int s = 0; s < 4; s++) {                                        \
      float4 va = *(const float4*)(wrow + s*8);                          \
      float4 vb4 = *(const float4*)(wrow + s*8 + 4);                     \
      float wv[8] = {va.x,va.y,va.z,va.w,vb4.x,vb4.y,vb4.z,vb4.w};       \
      half8 hv, lv;                                                      \
      _Pragma("unroll")                                                  \
      for (int jj = 0; jj < 8; jj++) {                                   \
        int cg = g*64 + (KC)*32 + s*8 + jj;                              \
        float scaled = wv[jj] * sh.svL[cg];                              \
        biasacc = fmaf(wv[jj], sh.svmuL[cg], biasacc);                   \
        _Float16 h = (_Float16)scaled;                                   \
        hv[jj] = h;                                                      \
        lv[jj] = (_Float16)(scaled - (float)h);                          \
      }                                                                  \
      int swz = (s ^ (o & 3) ^ ((o >> 2) & 3)) & 3;                      \
      int sidx = (g*64 + o)*32 + (swz << 3);                             \
      *(half8*)(sh.Whi + sidx) = hv;                                     \
      *(half8*)(sh.Wlo + sidx) = lv;                                     \
    }                                                                    \
  }

  // ---- MFMA over one kc's staged planes ----
#define MFMAS()                                                          \
  {                                                                      \
    half8 ahi[3], alo[3];                                                \
    int oa = wt*16 + (lane & 15);                                        \
    int c4 = lane >> 4;                                                  \
    int slotx = (c4 ^ (oa & 3) ^ ((oa >> 2) & 3)) & 3;                   \
    _Pragma("unroll")                                                    \
    for (int g = 0; g < 3; g++) {                                        \
      int sidx = (g*64 + oa)*32 + (slotx << 3);                          \
      ahi[g] = *(const half8*)(sh.Whi + sidx);                           \
      alo[g] = *(const half8*)(sh.Wlo + sidx);                           \
    }                                                                    \
    _Pragma("unroll")                                                    \
    for (int n = 0; n < 12; n++) {                                       \
      int px = n*16 + (lane & 15);                                       \
      int bidx = (c4*192 + (px ^ c4))*8;                                 \
      half8 bh = *(const half8*)(sh.Bhi + bidx);                         \
      half8 bl = *(const half8*)(sh.Blo + bidx);                         \
      accB[n] = __builtin_amdgcn_mfma_f32_16x16x32_f16(ahi[1], bh, accB[n], 0,0,0); \
      accB[n] = __builtin_amdgcn_mfma_f32_16x16x32_f16(ahi[1], bl, accB[n], 0,0,0); \
      accB[n] = __builtin_amdgcn_mfma_f32_16x16x32_f16(alo[1], bh, accB[n], 0,0,0); \
      accC[n] = __builtin_amdgcn_mfma_f32_16x16x32_f16(ahi[2], bh, accC[n], 0,0,0); \
      accC[n] = __builtin_amdgcn_mfma_f32_16x16x32_f16(ahi[2], bl, accC[n], 0,0,0); \
      accC[n] = __builtin_amdgcn_mfma_f32_16x16x32_f16(alo[2], bh, accC[n], 0,0,0); \
      if (n >= 4 && n < 8) {                                             \
        accA[n-4] = __builtin_amdgcn_mfma_f32_16x16x32_f16(ahi[0], bh, accA[n-4], 0,0,0); \
        accA[n-4] = __builtin_amdgcn_mfma_f32_16x16x32_f16(ahi[0], bl, accA[n-4], 0,0,0); \
        accA[n-4] = __builtin_amdgcn_mfma_f32_16x16x32_f16(alo[0], bh, accA[n-4], 0,0,0); \
      }                                                                  \
    }                                                                    \
  }

  LOADW(0, xw0)
  __syncthreads();          // svL/bvecL ready
  PACKW(xw0)
  WSTAGE(0)
  __syncthreads();          // kc0 planes ready
  LOADW(1, xw1)             // prefetch kc1 (global) under kc0 MFMAs
  MFMAS()
  __syncthreads();          // kc0 reads done, safe to overwrite
  PACKW(xw1)
  WSTAGE(1)
  __syncthreads();          // kc1 planes ready
  MFMAS()

  if (t < 192) sh.biasL[t] = biasacc;
  __syncthreads();

  // ---- epilogue: in-register sobel on mixed images + bias + residual ----
#pragma unroll
  for (int j = 0; j < 4; j++) {
    int o = wt*16 + ((lane >> 4) << 2) + j;
    float Sx[4], Sy[4];
#pragma unroll
    for (int nc = 0; nc < 4; nc++) {
      Sx[nc] = accB[nc][j] + 2.f*accB[4+nc][j] + accB[8+nc][j];
      Sy[nc] = accC[8+nc][j] - accC[nc][j];
    }
    float bt = sh.bvecL[o] - sh.biasL[o] - sh.biasL[64+o] - sh.biasL[128+o];
#pragma unroll
    for (int nc = 0; nc < 4; nc++) {
      int nm = (nc > 0) ? nc-1 : 0;
      int np = (nc < 3) ? nc+1 : 3;
      float xl1 = __shfl(Sx[nc], (lane - 1) & 63);
      float xl2 = (nc > 0) ? __shfl(Sx[nm], (lane + 15) & 63) : 0.f;
      float xL  = (lane & 15) ? xl1 : xl2;
      float xr1 = __shfl(Sx[nc], (lane + 1) & 63);
      float xr2 = (nc < 3) ? __shfl(Sx[np], (lane - 15) & 63) : 0.f;
      float xR  = ((lane & 15) == 15) ? xr2 : xr1;
      float yl1 = __shfl(Sy[nc], (lane - 1) & 63);
      float yl2 = (nc > 0) ? __shfl(Sy[nm], (lane + 15) & 63) : 0.f;
      float yL  = (lane & 15) ? yl1 : yl2;
      float yr1 = __shfl(Sy[nc], (lane + 1) & 63);
      float yr2 = (nc < 3) ? __shfl(Sy[np], (lane - 15) & 63) : 0.f;
      float yR  = ((lane & 15) == 15) ? yr2 : yr1;
      float gx = (xR - xL) * 0.125f;
      float gy = (yL + 2.f*Sy[nc] + yR) * 0.125f;
      float nw = accA[nc][j] + gx + gy + bt;
      int wpx = nc*16 + (lane & 15);
      size_t gi = (size_t)(b*NC + o)*HW + (size_t)r*64 + wpx;
      float nv = st[gi] + leak * nw;
      stn[gi] = nv;
      if (last && o < 3) {
        size_t oi = (size_t)(b*3 + o)*HW + (size_t)r*64 + wpx;
        out2[oi] = nv;
        out0[oi] = fminf(fmaxf(nv, -1.f), 1.f);
      }
    }
  }
#undef LOADW
#undef PACKW
#undef WSTAGE
#undef MFMAS
}

extern "C" void kernel_launch(void* const* d_in, const int* in_sizes, int n_in,
                              void* d_out, int out_size, void* d_ws, size_t ws_size,
                              hipStream_t stream) {
  const float* lat   = (const float*)d_in[0];
  const float* Wk    = (const float*)d_in[1];
  const float* bk    = (const float*)d_in[2];
  const float* Wb    = (const float*)d_in[3];
  const float* bb    = (const float*)d_in[4];
  const float* leakp = (const float*)d_in[5];
  float* out = (float*)d_out;
  float* ws  = (float*)d_ws;
  float* wT    = ws + WS_WT;
  float* bvec  = ws + WS_BV;
  float* latT  = ws + WS_LATT;
  float* svbuf = ws + WS_SV;
  float* svmub = ws + WS_SVMU;
  float* out0 = out;
  float* embs = out + 196608;
  float* out2 = out + 196608 + 17*SLICE;

  hipLaunchKernelGGL(k_latT, dim3(1),    dim3(256), 0, stream, lat, latT);
  hipLaunchKernelGGL(k_w,    dim3(49),   dim3(256), 0, stream, latT, Wk, bk, Wb, bb, wT, bvec);
  hipLaunchKernelGGL(k_init, dim3(4096), dim3(256), 0, stream, embs);
  for (int tstep = 0; tstep < NSTEP; tstep++) {
    const float* stc = embs + (size_t)tstep*SLICE;
    float*       stn = embs + (size_t)(tstep+1)*SLICE;
    hipLaunchKernelGGL(k_stats, dim3(64,16), dim3(256), 0, stream, stc, svbuf, svmub);
    hipLaunchKernelGGL(k_fused, dim3(1024), dim3(256), 0, stream,
                       stc, stn, wT, bvec, svbuf, svmub, leakp,
                       out0, out2, (int)(tstep == NSTEP-1));
  }
}

// Round 7
// 599.833 us; speedup vs baseline: 3.9708x; 1.0000x over previous
//
#include <hip/hip_runtime.h>
#include <cstdint>
#include <cstddef>

#define NB 16
#define NC 64
#define HW 4096
#define SLICE ((size_t)(NB*NC*HW))   // 4194304 floats per state
#define NSTEP 16

// ws layout (float offsets)
#define WS_WT    ((size_t)0)          // wT  [16][3][64 o][64 c] = 196608
#define WS_BV    ((size_t)196608)     // bvec[16][64]            = 1024
#define WS_LATT  ((size_t)197632)     // latT[512][16]           = 8192
#define WS_SV    ((size_t)205824)     // sv  [16][3][64]         = 3072
#define WS_SVMU  ((size_t)208896)     // svmu[16][3][64]         = 3072

typedef _Float16 half8 __attribute__((ext_vector_type(8)));  // 8 f16 (4 VGPRs)
typedef float f32x4 __attribute__((ext_vector_type(4)));     // MFMA acc

__global__ void k_latT(const float* __restrict__ lat, float* __restrict__ latT) {
  int t = threadIdx.x;
  for (int idx = t; idx < 16*512; idx += 256) {
    int b = idx >> 9, k = idx & 511;
    latT[k*16 + b] = lat[idx];
  }
}

// wT[b][g][o][c] = (lat @ Wk + bk) at j = o*192 + (g*64+c) ; bvec = lat @ Wb + bb
__global__ __launch_bounds__(256) void k_w(const float* __restrict__ latT,
    const float* __restrict__ Wk, const float* __restrict__ bk,
    const float* __restrict__ Wb, const float* __restrict__ bb,
    float* __restrict__ wT, float* __restrict__ bvec) {
  int t = threadIdx.x;
  if (blockIdx.x < 48) {
    int j = blockIdx.x*256 + t;
    float acc[16];
#pragma unroll
    for (int b = 0; b < 16; b++) acc[b] = 0.f;
#pragma unroll 4
    for (int k = 0; k < 512; k++) {
      float wv = Wk[(size_t)k*12288 + j];
      const float* lt = (const float*)__builtin_assume_aligned(latT + k*16, 64);
#pragma unroll
      for (int b = 0; b < 16; b++) acc[b] = fmaf(lt[b], wv, acc[b]);
    }
    int o = j / 192, cf = j % 192;
    int g = cf >> 6, c = cf & 63;
    float bkj = bk[j];
#pragma unroll
    for (int b = 0; b < 16; b++)
      wT[(((size_t)(b*3 + g))*64 + o)*64 + c] = acc[b] + bkj;
  } else if (t < 64) {
    int j = t;
    float acc[16];
#pragma unroll
    for (int b = 0; b < 16; b++) acc[b] = 0.f;
    for (int k = 0; k < 512; k++) {
      float wv = Wb[k*64 + j];
      const float* lt = (const float*)__builtin_assume_aligned(latT + k*16, 64);
#pragma unroll
      for (int b = 0; b < 16; b++) acc[b] = fmaf(lt[b], wv, acc[b]);
    }
    float bbj = bb[j];
#pragma unroll
    for (int b = 0; b < 16; b++) bvec[b*64 + j] = acc[b] + bbj;
  }
}

__global__ void k_init(float* __restrict__ e0) {
  int idx4 = (blockIdx.x*256 + threadIdx.x) * 4;
  float4 v = make_float4(0.f, 0.f, 0.f, 0.f);
  if ((idx4 & 262143) == 2080) v.x = 1.0f;  // 32*64+32, channel 0
  *(float4*)(e0 + idx4) = v;
}

// per (b,c): moments of st, gx, gy via separable sobel.
// No image LDS: thread = column w, wave = 16-row band; neighbors via shfl.
__global__ __launch_bounds__(256) void k_stats(const float* __restrict__ st,
    float* __restrict__ svb, float* __restrict__ svmub) {
  int c = blockIdx.x, b = blockIdx.y, t = threadIdx.x;
  __shared__ float red[4][6];
  const float* base = st + (size_t)(b*NC + c) * HW;
  int w = t & 63, wv = t >> 6, h0 = wv * 16;
  float s0=0,q0=0,s1=0,q1=0,s2=0,q2=0;

  float d_prev=0.f, s_prev=0.f, d_cur, s_cur, v_cur;
#define MKDS(X, D, S)                                  \
  {                                                    \
    float xl = __shfl((X), (w + 63) & 63);             \
    float xr = __shfl((X), (w + 1) & 63);              \
    if (w == 0)  xl = 0.f;                             \
    if (w == 63) xr = 0.f;                             \
    (D) = xr - xl; (S) = xl + 2.f*(X) + xr;            \
  }
  if (h0 > 0) {
    float x = base[(h0-1)*64 + w];
    MKDS(x, d_prev, s_prev)
  }
  {
    float x = base[h0*64 + w];
    MKDS(x, d_cur, s_cur)
    v_cur = x;
  }
#pragma unroll
  for (int k = 0; k < 16; k++) {
    int hn = h0 + k + 1;
    float d_nxt=0.f, s_nxt=0.f, v_nxt=0.f;
    if (hn < 64) {                  // wave-uniform
      float x = base[hn*64 + w];
      MKDS(x, d_nxt, s_nxt)
      v_nxt = x;
    }
    float gx = (d_prev + 2.f*d_cur + d_nxt) * 0.125f;
    float gy = (s_nxt - s_prev) * 0.125f;
    s0 += v_cur; q0 = fmaf(v_cur, v_cur, q0);
    s1 += gx;    q1 = fmaf(gx, gx, q1);
    s2 += gy;    q2 = fmaf(gy, gy, q2);
    d_prev = d_cur; s_prev = s_cur;
    d_cur = d_nxt; s_cur = s_nxt; v_cur = v_nxt;
  }
#undef MKDS
#pragma unroll
  for (int off = 32; off >= 1; off >>= 1) {
    s0 += __shfl_xor(s0, off); q0 += __shfl_xor(q0, off);
    s1 += __shfl_xor(s1, off); q1 += __shfl_xor(q1, off);
    s2 += __shfl_xor(s2, off); q2 += __shfl_xor(q2, off);
  }
  int lane = t & 63;
  if (lane == 0) {
    red[wv][0]=s0; red[wv][1]=q0; red[wv][2]=s1;
    red[wv][3]=q1; red[wv][4]=s2; red[wv][5]=q2;
  }
  __syncthreads();
  if (t == 0) {
    float r[6];
#pragma unroll
    for (int u = 0; u < 6; u++) r[u] = red[0][u]+red[1][u]+red[2][u]+red[3][u];
#pragma unroll
    for (int g = 0; g < 3; g++) {
      float mu  = r[2*g] * (1.f/HW);
      float var = fmaxf(r[2*g+1]*(1.f/HW) - mu*mu, 0.f);
      float sv  = 1.f / sqrtf(var + 1e-5f);
      svb  [b*192 + g*64 + c] = sv;
      svmub[b*192 + g*64 + c] = sv * mu;
    }
  }
}

struct SB2 {
  alignas(16) _Float16 Bhi[6144];      // [c8][px^c8][cj] (per row,kc staging)
  alignas(16) _Float16 Blo[6144];
  alignas(16) _Float16 Whi[2][6144];   // [kc][g][o][slot-swizzled c_rel]
  alignas(16) _Float16 Wlo[2][6144];
  float svL[192], svmuL[192], biasL[192], bvecL[64];
};  // ~74.5 KB -> 2 blocks/CU

// Fused: mix raw st with scaled W (MFMA f16 hi/lo), sobel AFTER mix, residual.
// Grid 512: bid -> b = bid>>5, xcd = bid&7, sub = (bid>>3)&3; rows r0, r0+1.
__global__ __launch_bounds__(256, 2) void k_fused(const float* __restrict__ st,
    float* __restrict__ stn, const float* __restrict__ wT,
    const float* __restrict__ bvec, const float* __restrict__ svb,
    const float* __restrict__ svmub, const float* __restrict__ leakp,
    float* __restrict__ out0, float* __restrict__ out2, int last) {
  __shared__ SB2 sh;
  int bid = blockIdx.x, t = threadIdx.x;
  int b = bid >> 5;
  int r0 = (bid & 7) * 8 + ((bid >> 3) & 3) * 2;
  int lane = t & 63, wt = t >> 6;
  const float* stb = st + (size_t)b*NC*HW;
  float leak = fminf(fmaxf(leakp[0], 0.001f), 1000.f);

  if (t < 192) { sh.svL[t] = svb[b*192 + t]; sh.svmuL[t] = svmub[b*192 + t]; }
  if (t < 64) sh.bvecL[t] = bvec[b*64 + t];
  __syncthreads();          // sv ready

  // ---- stage scaled W (hi/lo f16) for BOTH kc + bias dot, once per block ----
  if (t < 192) {
    int g = t >> 6, o = t & 63;
    float biasacc = 0.f;
#pragma unroll
    for (int kc = 0; kc < 2; kc++) {
      const float* wrow = wT + (((size_t)(b*3 + g))*64 + o)*64 + kc*32;
#pragma unroll
      for (int s = 0; s < 4; s++) {
        float4 va = *(const float4*)(wrow + s*8);
        float4 vb4 = *(const float4*)(wrow + s*8 + 4);
        float wv[8] = {va.x,va.y,va.z,va.w,vb4.x,vb4.y,vb4.z,vb4.w};
        half8 hv, lv;
#pragma unroll
        for (int jj = 0; jj < 8; jj++) {
          int cg = g*64 + kc*32 + s*8 + jj;
          float scaled = wv[jj] * sh.svL[cg];
          biasacc = fmaf(wv[jj], sh.svmuL[cg], biasacc);
          _Float16 h = (_Float16)scaled;
          hv[jj] = h;
          lv[jj] = (_Float16)(scaled - (float)h);
        }
        int swz = (s ^ (o & 3) ^ ((o >> 2) & 3)) & 3;
        int sidx = (g*64 + o)*32 + (swz << 3);
        *(half8*)(&sh.Whi[kc][sidx]) = hv;
        *(half8*)(&sh.Wlo[kc][sidx]) = lv;
      }
    }
    sh.biasL[t] = biasacc;
  }

  // ---- direct transposed window load: unit u=(c8,pxu); 8 channel-strided floats ----
#define LOADW(KC, R, XW)                                                 \
  _Pragma("unroll")                                                      \
  for (int i = 0; i < 3; i++) {                                          \
    int u = t + i*256;                                                   \
    int c8 = u / 192, pxu = u % 192;                                     \
    int rho = pxu >> 6, ww = pxu & 63;                                   \
    int row = (R) - 1 + rho;                                             \
    bool ok = (row >= 0) && (row < 64);                                  \
    int rowc = ok ? row : 0;                                             \
    const float* gp = stb + (size_t)((KC)*32 + c8*8)*HW + rowc*64 + ww;  \
    _Pragma("unroll")                                                    \
    for (int ii = 0; ii < 8; ii++) {                                     \
      float val = gp[(size_t)ii*HW];                                     \
      XW[i][ii] = ok ? val : 0.f;                                        \
    }                                                                    \
  }

#define PACKW(XW)                                                        \
  _Pragma("unroll")                                                      \
  for (int i = 0; i < 3; i++) {                                          \
    int u = t + i*256;                                                   \
    int c8 = u / 192, pxu = u % 192;                                     \
    half8 hv, lv;                                                        \
    _Pragma("unroll")                                                    \
    for (int ii = 0; ii < 8; ii++) {                                     \
      float x = XW[i][ii];                                               \
      _Float16 h = (_Float16)x;                                          \
      hv[ii] = h;                                                        \
      lv[ii] = (_Float16)(x - (float)h);                                 \
    }                                                                    \
    int di = (c8*192 + (pxu ^ c8)) * 8;                                  \
    *(half8*)(sh.Bhi + di) = hv;                                         \
    *(half8*)(sh.Blo + di) = lv;                                         \
  }

#define MFMAS(KC)                                                        \
  {                                                                      \
    half8 ahi[3], alo[3];                                                \
    int oa = wt*16 + (lane & 15);                                        \
    int c4 = lane >> 4;                                                  \
    int slotx = (c4 ^ (oa & 3) ^ ((oa >> 2) & 3)) & 3;                   \
    _Pragma("unroll")                                                    \
    for (int g = 0; g < 3; g++) {                                        \
      int sidx = (g*64 + oa)*32 + (slotx << 3);                          \
      ahi[g] = *(const half8*)(&sh.Whi[KC][sidx]);                       \
      alo[g] = *(const half8*)(&sh.Wlo[KC][sidx]);                       \
    }                                                                    \
    _Pragma("unroll")                                                    \
    for (int n = 0; n < 12; n++) {                                       \
      int px = n*16 + (lane & 15);                                       \
      int bidx = (c4*192 + (px ^ c4))*8;                                 \
      half8 bh = *(const half8*)(sh.Bhi + bidx);                         \
      half8 bl = *(const half8*)(sh.Blo + bidx);                         \
      accB[n] = __builtin_amdgcn_mfma_f32_16x16x32_f16(ahi[1], bh, accB[n], 0,0,0); \
      accB[n] = __builtin_amdgcn_mfma_f32_16x16x32_f16(ahi[1], bl, accB[n], 0,0,0); \
      accB[n] = __builtin_amdgcn_mfma_f32_16x16x32_f16(alo[1], bh, accB[n], 0,0,0); \
      accC[n] = __builtin_amdgcn_mfma_f32_16x16x32_f16(ahi[2], bh, accC[n], 0,0,0); \
      accC[n] = __builtin_amdgcn_mfma_f32_16x16x32_f16(ahi[2], bl, accC[n], 0,0,0); \
      accC[n] = __builtin_amdgcn_mfma_f32_16x16x32_f16(alo[2], bh, accC[n], 0,0,0); \
      if (n >= 4 && n < 8) {                                             \
        accA[n-4] = __builtin_amdgcn_mfma_f32_16x16x32_f16(ahi[0], bh, accA[n-4], 0,0,0); \
        accA[n-4] = __builtin_amdgcn_mfma_f32_16x16x32_f16(ahi[0], bl, accA[n-4], 0,0,0); \
        accA[n-4] = __builtin_amdgcn_mfma_f32_16x16x32_f16(alo[0], bh, accA[n-4], 0,0,0); \
      }                                                                  \
    }                                                                    \
  }

#pragma unroll
  for (int rr = 0; rr < 2; rr++) {
    int r = r0 + rr;
    f32x4 accA[4] = {}; f32x4 accB[12] = {}; f32x4 accC[12] = {};
    float xw0[3][8], xw1[3][8];

    LOADW(0, r, xw0)
    __syncthreads();        // iter0: W/bias ready; iter1: prior B reads done
    PACKW(xw0)
    __syncthreads();        // kc0 planes ready
    LOADW(1, r, xw1)        // prefetch kc1 under kc0 MFMAs
    MFMAS(0)
    __syncthreads();        // kc0 B reads done
    PACKW(xw1)
    __syncthreads();        // kc1 planes ready
    MFMAS(1)

    // ---- epilogue: in-register sobel on mixed images + bias + residual ----
#pragma unroll
    for (int j = 0; j < 4; j++) {
      int o = wt*16 + ((lane >> 4) << 2) + j;
      float Sx[4], Sy[4];
#pragma unroll
      for (int nc = 0; nc < 4; nc++) {
        Sx[nc] = accB[nc][j] + 2.f*accB[4+nc][j] + accB[8+nc][j];
        Sy[nc] = accC[8+nc][j] - accC[nc][j];
      }
      float bt = sh.bvecL[o] - sh.biasL[o] - sh.biasL[64+o] - sh.biasL[128+o];
#pragma unroll
      for (int nc = 0; nc < 4; nc++) {
        int nm = (nc > 0) ? nc-1 : 0;
        int np = (nc < 3) ? nc+1 : 3;
        float xl1 = __shfl(Sx[nc], (lane - 1) & 63);
        float xl2 = (nc > 0) ? __shfl(Sx[nm], (lane + 15) & 63) : 0.f;
        float xL  = (lane & 15) ? xl1 : xl2;
        float xr1 = __shfl(Sx[nc], (lane + 1) & 63);
        float xr2 = (nc < 3) ? __shfl(Sx[np], (lane - 15) & 63) : 0.f;
        float xR  = ((lane & 15) == 15) ? xr2 : xr1;
        float yl1 = __shfl(Sy[nc], (lane - 1) & 63);
        float yl2 = (nc > 0) ? __shfl(Sy[nm], (lane + 15) & 63) : 0.f;
        float yL  = (lane & 15) ? yl1 : yl2;
        float yr1 = __shfl(Sy[nc], (lane + 1) & 63);
        float yr2 = (nc < 3) ? __shfl(Sy[np], (lane - 15) & 63) : 0.f;
        float yR  = ((lane & 15) == 15) ? yr2 : yr1;
        float gx = (xR - xL) * 0.125f;
        float gy = (yL + 2.f*Sy[nc] + yR) * 0.125f;
        float nw = accA[nc][j] + gx + gy + bt;
        int wpx = nc*16 + (lane & 15);
        size_t gi = (size_t)(b*NC + o)*HW + (size_t)r*64 + wpx;
        float nv = st[gi] + leak * nw;
        stn[gi] = nv;
        if (last && o < 3) {
          size_t oi = (size_t)(b*3 + o)*HW + (size_t)r*64 + wpx;
          out2[oi] = nv;
          out0[oi] = fminf(fmaxf(nv, -1.f), 1.f);
        }
      }
    }
  }
#undef LOADW
#undef PACKW
#undef MFMAS
}

extern "C" void kernel_launch(void* const* d_in, const int* in_sizes, int n_in,
                              void* d_out, int out_size, void* d_ws, size_t ws_size,
                              hipStream_t stream) {
  const float* lat   = (const float*)d_in[0];
  const float* Wk    = (const float*)d_in[1];
  const float* bk    = (const float*)d_in[2];
  const float* Wb    = (const float*)d_in[3];
  const float* bb    = (const float*)d_in[4];
  const float* leakp = (const float*)d_in[5];
  float* out = (float*)d_out;
  float* ws  = (float*)d_ws;
  float* wT    = ws + WS_WT;
  float* bvec  = ws + WS_BV;
  float* latT  = ws + WS_LATT;
  float* svbuf = ws + WS_SV;
  float* svmub = ws + WS_SVMU;
  float* out0 = out;
  float* embs = out + 196608;
  float* out2 = out + 196608 + 17*SLICE;

  hipLaunchKernelGGL(k_latT, dim3(1),    dim3(256), 0, stream, lat, latT);
  hipLaunchKernelGGL(k_w,    dim3(49),   dim3(256), 0, stream, latT, Wk, bk, Wb, bb, wT, bvec);
  hipLaunchKernelGGL(k_init, dim3(4096), dim3(256), 0, stream, embs);
  for (int tstep = 0; tstep < NSTEP; tstep++) {
    const float* stc = embs + (size_t)tstep*SLICE;
    float*       stn = embs + (size_t)(tstep+1)*SLICE;
    hipLaunchKernelGGL(k_stats, dim3(64,16), dim3(256), 0, stream, stc, svbuf, svmub);
    hipLaunchKernelGGL(k_fused, dim3(512), dim3(256), 0, stream,
                       stc, stn, wT, bvec, svbuf, svmub, leakp,
                       out0, out2, (int)(tstep == NSTEP-1));
  }
}